// Round 1
// baseline (276.149 us; speedup 1.0000x reference)
//
#include <hip/hip_runtime.h>

// MAUCHLoss: B=2097152 rows, C=15 categories, f32 inputs.
// ws layout (46 floats): [0..14] sum(sig) per cat, [15..29] sum(sig*label),
// [30..44] sum(label) (npos), [45] sum(sp + (1-label)*sig) for CEL.

#define CATS 15
#define NBLOCKS 960   // 960*256*4 = 983040 = 15*65536 -> per-thread category phase is constant
#define NTHREADS 256

__global__ __launch_bounds__(NTHREADS) void mauch_main(
    const float* __restrict__ outp, const float* __restrict__ labp,
    float* __restrict__ ws, int nFloat4)
{
    const int t = blockIdx.x * blockDim.x + threadIdx.x;
    const int stride = gridDim.x * blockDim.x;   // stride*4 % 15 == 0

    float ssig[4]  = {0.f, 0.f, 0.f, 0.f};
    float spos[4]  = {0.f, 0.f, 0.f, 0.f};
    float snp[4]   = {0.f, 0.f, 0.f, 0.f};
    float cel = 0.f;

    const float4* o4 = (const float4*)outp;
    const float4* l4 = (const float4*)labp;

    for (int f = t; f < nFloat4; f += stride) {
        float4 ov = o4[f];
        float4 lv = l4[f];
#pragma unroll
        for (int j = 0; j < 4; ++j) {
            float x = (&ov.x)[j];
            float l = (&lv.x)[j];
            // sig = sigmoid(x)
            float e   = __expf(-x);
            float sig = __builtin_amdgcn_rcpf(1.0f + e);
            // sp = log(1 + exp(-sig)) = -log(sigmoid(sig));  sig in (0,1) -> stable
            float sp  = __logf(1.0f + __expf(-sig));
            ssig[j] += sig;
            spos[j] += sig * l;
            snp[j]  += l;
            cel     += sp + (1.0f - l) * sig;
        }
    }

    __shared__ float red[3 * CATS + 1];
    for (int i = threadIdx.x; i < 3 * CATS + 1; i += blockDim.x) red[i] = 0.f;
    __syncthreads();

    // element categories for this thread: (4t + j) mod 15, constant across iterations
    int base = (4 * t) % CATS;
#pragma unroll
    for (int j = 0; j < 4; ++j) {
        int c = base + j; if (c >= CATS) c -= CATS;
        atomicAdd(&red[c],            ssig[j]);
        atomicAdd(&red[CATS + c],     spos[j]);
        atomicAdd(&red[2 * CATS + c], snp[j]);
    }
    atomicAdd(&red[3 * CATS], cel);
    __syncthreads();

    for (int i = threadIdx.x; i < 3 * CATS + 1; i += blockDim.x)
        atomicAdd(&ws[i], red[i]);
}

__global__ void mauch_final(const float* __restrict__ ws, float* __restrict__ out,
                            float invBC, float rowsB)
{
    if (threadIdx.x == 0 && blockIdx.x == 0) {
        float sum_term = 0.f, pen_last = 0.f;
#pragma unroll
        for (int c = 0; c < CATS; ++c) {
            float ssig = ws[c];
            float sp   = ws[CATS + c];
            float np   = ws[2 * CATS + c];
            float nn   = rowsB - np;
            float sneg = ssig - sp;
            float mp = (np > 0.f) ? sp   / fmaxf(np, 1.f) : 0.f;
            float mn = (nn > 0.f) ? sneg / fmaxf(nn, 1.f) : 0.f;
            float pen = 1.f - mp + mn;
            sum_term += pen;
            if (c == CATS - 1) pen_last = pen;
        }
        float cel = ws[3 * CATS] * invBC;
        out[0] = cel + 0.1f * (sum_term / 15.f);
        out[1] = 0.1f * pen_last;
    }
}

extern "C" void kernel_launch(void* const* d_in, const int* in_sizes, int n_in,
                              void* d_out, int out_size, void* d_ws, size_t ws_size,
                              hipStream_t stream) {
    const float* outp = (const float*)d_in[0];
    const float* labp = (const float*)d_in[1];
    float* out = (float*)d_out;
    float* ws  = (float*)d_ws;

    const int total   = in_sizes[0];          // B * 15
    const int nFloat4 = total / 4;
    const float rowsB = (float)(total / CATS);
    const float invBC = 1.0f / (float)total;

    // ws is re-poisoned before every timed launch -> zero it (capture-safe async memset)
    hipMemsetAsync(ws, 0, (3 * CATS + 1) * sizeof(float), stream);

    mauch_main<<<NBLOCKS, NTHREADS, 0, stream>>>(outp, labp, ws, nFloat4);
    mauch_final<<<1, 64, 0, stream>>>(ws, out, invBC, rowsB);
}